// Round 9
// baseline (1217.869 us; speedup 1.0000x reference)
//
#include <hip/hip_runtime.h>
#include <math.h>

// TreeLSTM MI355X — R9: barrier-free steady-state K-loop.
// Weights pre-swizzled to MFMA fragment order (Wfrag) -> B loads are
// 1KB-coalesced global->VGPR, L1/L2-hot, no LDS/no barrier. A staged once
// to LDS frag-order via DMA16 (+1 barrier). Block = 128 child rows (64
// parents) x 64 cols x 4 gates; acc=128 VGPR; 2 blocks/CU.
// ws ~235 MB: WxV | leafH | hUp | cA | cB(=emb16+Wx16) | rep | W16 | Wfrag

typedef _Float16 h16;
typedef h16 f16x8 __attribute__((ext_vector_type(8)));
typedef float f32x4 __attribute__((ext_vector_type(4)));

#define HS 256
#define NTREE 1023
#define B2 256

#define DMA16(gp, lp) __builtin_amdgcn_global_load_lds( \
    (const __attribute__((address_space(1))) void*)(gp), \
    (__attribute__((address_space(3))) void*)(lp), 16, 0, 0)

__device__ __forceinline__ float sigf(float x){
  return 1.0f/(1.0f + exp2f(x * -1.44269504f));
}
__device__ __forceinline__ float tanh_fast(float x){
  return 2.0f/(1.0f + exp2f(x * -2.88539008f)) - 1.0f;
}

// ------------- convert fp32 -> fp16 (emb, Ufw, Uiou, Wiou) + zero rep -------
__global__ __launch_bounds__(256) void convert_all(const float* __restrict__ emb,
    const float* __restrict__ Ufw, const float* __restrict__ Uiou,
    const float* __restrict__ Wiou, h16* __restrict__ emb16,
    h16* __restrict__ W16, h16* __restrict__ Wx16, float* __restrict__ rep){
  if (blockIdx.x < 64)
    ((float4*)rep)[blockIdx.x*256 + threadIdx.x] = make_float4(0.f,0.f,0.f,0.f);
  const size_t i0 = ((size_t)blockIdx.x*256 + threadIdx.x)*8;
  const float* src; h16* dst; size_t off;
  if (i0 < 8192000UL){ src = emb;  dst = emb16;       off = i0; }
  else if (i0 < 8257536UL){ src = Ufw;  dst = W16;        off = i0 - 8192000UL; }
  else if (i0 < 8454144UL){ src = Uiou; dst = W16+65536;  off = i0 - 8257536UL; }
  else               { src = Wiou; dst = Wx16;       off = i0 - 8454144UL; }
  const float4 v0 = *(const float4*)&src[off];
  const float4 v1 = *(const float4*)&src[off+4];
  f16x8 o;
  o[0]=(h16)v0.x; o[1]=(h16)v0.y; o[2]=(h16)v0.z; o[3]=(h16)v0.w;
  o[4]=(h16)v1.x; o[5]=(h16)v1.y; o[6]=(h16)v1.z; o[7]=(h16)v1.w;
  *(f16x8*)&dst[off] = o;
}

// ------------- swizzle W16 into MFMA fragment order -------------
// Wfrag[(((cb*8 + kc)*16 + f)*64 + lane)*8 + j]
//   = W16[(g*256 + cb*64 + cf*16 + (lane&15)) * 256 + kc*32 + (lane>>4)*8 + j]
// where f = g*4 + cf  (g = gate 0..3 -> W16 row block; cf = 16-col frag 0..3)
__global__ __launch_bounds__(256) void swizzle_w(const h16* __restrict__ W16,
    h16* __restrict__ Wfrag){
  const int tid = blockIdx.x*256 + threadIdx.x;   // 0..65535
  const int lane = tid & 63;
  const int f    = (tid >> 6) & 15;
  const int kc   = (tid >> 10) & 7;
  const int cb   = tid >> 13;
  const int g = f >> 2, cf = f & 3;
  const int row = g*256 + cb*64 + cf*16 + (lane & 15);
  const int col = kc*32 + (lane >> 4)*8;
  const f16x8 v = *(const f16x8*)&W16[(size_t)row*256 + col];
  *(f16x8*)&Wfrag[(size_t)tid*8] = v;
}

// ------------- WxV = emb16 @ Wx16^T : M=32000, N=768, K=256 (MFMA) -------------
__global__ __launch_bounds__(256) void wxv_mfma(const h16* __restrict__ emb16,
    const h16* __restrict__ Wx16, h16* __restrict__ WxV){
  __shared__ h16 As[64*40];
  __shared__ h16 Bs[64*40];
  const int t = threadIdx.x, lane = t & 63, wave = t >> 6;
  const int q = lane >> 4, li = lane & 15;
  const int waveR = wave & 1, waveC = wave >> 1;
  const int bm = blockIdx.x*64, bn = blockIdx.y*64;
  const size_t aAddr = ((size_t)(bm + (t>>2)))*256 + (t&3)*8;
  const size_t bAddr = ((size_t)(bn + (t>>2)))*256 + (t&3)*8;
  const int ldsOff = (t>>2)*40 + (t&3)*8;
  f32x4 acc[2][2] = {};
  for (int k0 = 0; k0 < 256; k0 += 32){
    const f16x8 a = *(const f16x8*)&emb16[aAddr + k0];
    const f16x8 b = *(const f16x8*)&Wx16[bAddr + k0];
    __syncthreads();
    *(f16x8*)&As[ldsOff] = a;
    *(f16x8*)&Bs[ldsOff] = b;
    __syncthreads();
    #pragma unroll
    for (int rt=0; rt<2; ++rt){
      const f16x8 av = *(const f16x8*)&As[(waveR*32 + rt*16 + li)*40 + q*8];
      #pragma unroll
      for (int ct=0; ct<2; ++ct){
        const f16x8 bv = *(const f16x8*)&Bs[(waveC*32 + ct*16 + li)*40 + q*8];
        acc[rt][ct] = __builtin_amdgcn_mfma_f32_16x16x32_f16(av, bv, acc[rt][ct], 0,0,0);
      }
    }
  }
  #pragma unroll
  for (int rt=0; rt<2; ++rt)
    #pragma unroll
    for (int ct=0; ct<2; ++ct){
      const int col = bn + waveC*32 + ct*16 + li;
      #pragma unroll
      for (int reg=0; reg<4; ++reg){
        const int row = bm + waveR*32 + rt*16 + q*4 + reg;
        WxV[(size_t)row*768 + col] = (h16)acc[rt][ct][reg];
      }
    }
}

// ------------- leaves: gather WxV, cell, write h (c NOT stored) -------------
__global__ __launch_bounds__(256) void leaf_kernel(const int* __restrict__ t1,
    const int* __restrict__ t2, const h16* __restrict__ WxV,
    const float* __restrict__ biou, h16* __restrict__ leafH){
  const int r = blockIdx.y, jg = blockIdx.x, k = threadIdx.x;
  const int* tp = (r < 128) ? t1 : t2;
  const int b = r & 127;
  const float bi = biou[k], bo = biou[256+k], bu = biou[512+k];
  #pragma unroll
  for (int jj=0; jj<8; ++jj){
    const int leafIdx = jg*8 + jj;
    const size_t v = (size_t)tp[b*NTREE + 511 + leafIdx];
    const float vi = (float)WxV[v*768 + k] + bi;
    const float vo = (float)WxV[v*768 + 256 + k] + bo;
    const float vu = (float)WxV[v*768 + 512 + k] + bu;
    const float c = sigf(vi) * tanh_fast(vu);
    const float h = sigf(vo) * tanh_fast(c);
    leafH[((size_t)r*512 + leafIdx)*HS + k] = (h16)h;
  }
}

// ------------- barrier-free fused MFMA level kernel -------------
// Block: 128 child rows (64 parents). ldsA[rf=8][kc=8][lane][16B] = 64 KB,
// staged once via DMA16 + 1 barrier. B from Wfrag, coalesced 1KB loads.
// 4 waves: waveR = 64-row half (rt 0..3 -> 16-row frags), waveC = 32-col half.
__global__ __launch_bounds__(256,2) void level_mfma(
    const h16* __restrict__ hChild, const h16* __restrict__ cChild,
    const h16* __restrict__ Wfrag,   // [cb=4][kc=8][f=16][lane=64][8]
    const h16* __restrict__ WxV,
    const int* __restrict__ t1, const int* __restrict__ t2,
    const float* __restrict__ biou, const float* __restrict__ Ufb,
    h16* __restrict__ hUp, h16* __restrict__ cPar,
    int log2n, int leafLvl, int cbN){
  const int n = 1 << log2n;
  const int mask2 = 2*n - 1;
  const int strideR = leafLvl ? 512 : 511;
  const int childBase = leafLvl ? 0 : mask2;
  __shared__ h16 ldsA[8*8*64*8];   // 64 KB
  const int t = threadIdx.x, w = t >> 6, l = t & 63;
  const int q = l >> 4, li = l & 15;
  const int waveR = w & 1, waveC = w >> 1;
  const int bx = blockIdx.x;

  // ---- stage A once: wave w stages rf = 2w, 2w+1 (frag-order) ----
  #pragma unroll
  for (int rf2=0; rf2<2; ++rf2){
    const int grow = bx*128 + (w*2 + rf2)*16 + li;
    const int rr = grow >> (log2n + 1);
    const size_t abase = ((size_t)rr*strideR + childBase + (grow & mask2))*256;
    #pragma unroll
    for (int kc=0; kc<8; ++kc)
      DMA16(hChild + abase + kc*32 + q*8, &ldsA[((w*2 + rf2)*8 + kc)*512]);
  }
  __syncthreads();   // only barrier in the kernel

  for (int cb=0; cb<cbN; ++cb){
    const int cbi = blockIdx.y*cbN + cb;           // 64-col group 0..3
    const int colBase = cbi*64;
    // wave's 8 B-fragments: f = g*4 + (waveC*2 + ct)
    const h16* bBase = Wfrag + ((size_t)cbi*8*16 + 0)*512 + l*8;

    f32x4 acc[4][4][2] = {};   // [gate f,i,o,u][rt][ct]
    #pragma unroll
    for (int kc=0; kc<8; ++kc){
      f16x8 bF[4][2];
      #pragma unroll
      for (int g=0; g<4; ++g)
        #pragma unroll
        for (int ct=0; ct<2; ++ct)
          bF[g][ct] = *(const f16x8*)(bBase +
              ((size_t)kc*16 + g*4 + waveC*2 + ct)*512);
      f16x8 aF[4];
      #pragma unroll
      for (int rt=0; rt<4; ++rt)
        aF[rt] = *(const f16x8*)&ldsA[(((waveR*4 + rt)*8 + kc)*64 + l)*8];
      #pragma unroll
      for (int g=0; g<4; ++g)
        #pragma unroll
        for (int rt=0; rt<4; ++rt)
          #pragma unroll
          for (int ct=0; ct<2; ++ct)
            acc[g][rt][ct] = __builtin_amdgcn_mfma_f32_16x16x32_f16(
                aF[rt], bF[g][ct], acc[g][rt][ct], 0,0,0);
    }

    // ---- epilogue (all lane-local; sibling pairs = adjacent C regs) ----
    #pragma unroll
    for (int ct=0; ct<2; ++ct){
      const int c = colBase + waveC*32 + ct*16 + li;
      const float fb  = Ufb[c];
      const float bi_ = biou[c], bo_ = biou[256+c], bu_ = biou[512+c];
      #pragma unroll
      for (int rt=0; rt<4; ++rt){
        #pragma unroll
        for (int pp=0; pp<2; ++pp){
          const int crel = waveR*64 + rt*16 + q*4 + 2*pp;  // even child row (rel)
          const int m = bx*64 + (crel >> 1);               // global parent index
          const int rr2 = m >> log2n;
          const int jn = m & (n - 1);
          const float fl = sigf(acc[0][rt][ct][2*pp]   + fb);
          const float fr = sigf(acc[0][rt][ct][2*pp+1] + fb);
          const float iv = acc[1][rt][ct][2*pp] + acc[1][rt][ct][2*pp+1] + bi_;
          const float ov = acc[2][rt][ct][2*pp] + acc[2][rt][ct][2*pp+1] + bo_;
          const float uv = acc[3][rt][ct][2*pp] + acc[3][rt][ct][2*pp+1] + bu_;
          float cl, cr;
          if (leafLvl){
            const int* tp = (rr2 < 128) ? t1 : t2;
            const int b = rr2 & 127;
            const size_t vl = (size_t)tp[b*NTREE + 511 + 2*jn];
            const size_t vr = (size_t)tp[b*NTREE + 512 + 2*jn];
            cl = sigf((float)WxV[vl*768 + c] + bi_) * tanh_fast((float)WxV[vl*768 + 512 + c] + bu_);
            cr = sigf((float)WxV[vr*768 + c] + bi_) * tanh_fast((float)WxV[vr*768 + 512 + c] + bu_);
          } else {
            const int cgl = bx*128 + crel;
            cl = (float)cChild[(size_t)cgl*256 + c];
            cr = (float)cChild[(size_t)(cgl+1)*256 + c];
          }
          const float cnew = sigf(iv)*tanh_fast(uv) + fl*cl + fr*cr;
          const float hnew = sigf(ov)*tanh_fast(cnew);
          hUp [((size_t)rr2*511 + (n-1) + jn)*256 + c] = (h16)hnew;
          cPar[((size_t)m)*256 + c] = (h16)cnew;
        }
      }
    }
  }
}

// ------------- rep accumulation -------------
__global__ __launch_bounds__(256) void rep_accum(const h16* __restrict__ H,
    float* __restrict__ rep, int nrows, int chunk){
  const int r = blockIdx.y, k = threadIdx.x;
  const int n0 = blockIdx.x * chunk;
  int n1 = n0 + chunk; if (n1 > nrows) n1 = nrows;
  float s = 0.f;
  for (int nd = n0; nd < n1; ++nd)
    s += (float)H[((size_t)r*nrows + nd)*HS + k];
  atomicAdd(&rep[r*HS + k], s);
}

// ------------- classifier -------------
__global__ __launch_bounds__(256) void cls_kernel(const float* __restrict__ rep,
    const float* __restrict__ clsw, const float* __restrict__ clsb,
    float* __restrict__ out){
  const int b = blockIdx.x, k = threadIdx.x;
  const float d = fabsf(rep[b*HS + k] - rep[(128+b)*HS + k]) * (1.0f/1023.0f);
  __shared__ float r0[256], r1[256];
  r0[k] = d * clsw[k];
  r1[k] = d * clsw[HS + k];
  __syncthreads();
  for (int off = 128; off > 0; off >>= 1){
    if (k < off){ r0[k] += r0[k+off]; r1[k] += r1[k+off]; }
    __syncthreads();
  }
  if (k == 0){
    out[b*2 + 0] = r0[0] + clsb[0];
    out[b*2 + 1] = r1[0] + clsb[1];
  }
}

extern "C" void kernel_launch(void* const* d_in, const int* in_sizes, int n_in,
                              void* d_out, int out_size, void* d_ws, size_t ws_size,
                              hipStream_t stream){
  const int*   types1 = (const int*)d_in[0];
  const int*   types2 = (const int*)d_in[1];
  const float* emb    = (const float*)d_in[2];
  const float* Wiou   = (const float*)d_in[3];
  const float* Uiou   = (const float*)d_in[4];
  const float* biou   = (const float*)d_in[5];
  const float* Ufw    = (const float*)d_in[6];
  const float* Ufb    = (const float*)d_in[7];
  const float* clsw   = (const float*)d_in[8];
  const float* clsb   = (const float*)d_in[9];
  float* out = (float*)d_out;

  h16* WxV   = (h16*)d_ws;                        // 24,576,000
  h16* leafH = WxV   + 24576000UL;                // 33,554,432
  h16* hUp   = leafH + 33554432UL;                // 33,488,896
  h16* cA    = hUp   + 33488896UL;                // 16,777,216
  h16* cB    = cA    + 16777216UL;                //  8,388,608
  h16* emb16 = cB;                                //  8,192,000 (overlay on cB)
  h16* Wx16  = cB + 8192000UL;                    //    196,608 (overlay on cB)
  float* rep = (float*)(cB + 8388608UL);          //     65,536 fp32
  h16* W16   = (h16*)(rep + 65536UL);             //    262,144
  h16* Wfrag = W16 + 262144UL;                    //    524,288 (1 MB)

  convert_all<<<4224, 256, 0, stream>>>(emb, Ufw, Uiou, Wiou, emb16, W16, Wx16, rep);
  swizzle_w<<<256, 256, 0, stream>>>(W16, Wfrag);
  wxv_mfma<<<dim3(500,12), 256, 0, stream>>>(emb16, Wx16, WxV);
  leaf_kernel<<<dim3(64, B2), 256, 0, stream>>>(types1, types2, WxV, biou, leafH);

  const h16* cprev = nullptr;
  for (int lvl = 8; lvl >= 0; --lvl){
    const int children = 512 << lvl;        // B2 * 2n
    const int cbN = (lvl >= 7) ? 4 : 1;     // big levels: y=1, col loop in-block
    h16* cout = ((8 - lvl) & 1) ? cB : cA;
    level_mfma<<<dim3(children/128, 4/cbN), 256, 0, stream>>>(
        (lvl == 8) ? leafH : hUp, cprev, Wfrag, WxV, types1, types2,
        biou, Ufb, hUp, cout, lvl, (lvl == 8) ? 1 : 0, cbN);
    cprev = cout;
  }
  rep_accum<<<dim3(4, B2), 256, 0, stream>>>(leafH, rep, 512, 128);
  rep_accum<<<dim3(4, B2), 256, 0, stream>>>(hUp,   rep, 511, 128);
  cls_kernel<<<128, 256, 0, stream>>>(rep, clsw, clsb, out);
}

// Round 10
// 655.928 us; speedup vs baseline: 1.8567x; 1.8567x over previous
//
#include <hip/hip_runtime.h>
#include <math.h>

// TreeLSTM MI355X — R10: R5/R8 structure + CONTIGUOUS B-DMA staging.
// Weights pre-swizzled (Wfrag, frag order) so every B DMA16 reads a
// contiguous 1KB (lane l -> base + l*16B) — no 16-line gathers in the
// repeated kc path. A staged once per block (scattered, one-time).
// Block = 64 child rows (32 parents); cb loop over 64-col groups x 4 gates.
// ws ~235 MB: WxV | leafH | hUp | cA | cB(=emb16+Wx16) | rep | W16 | Wfrag

typedef _Float16 h16;
typedef h16 f16x8 __attribute__((ext_vector_type(8)));
typedef float f32x4 __attribute__((ext_vector_type(4)));

#define HS 256
#define NTREE 1023
#define B2 256

#define DMA16(gp, lp) __builtin_amdgcn_global_load_lds( \
    (const __attribute__((address_space(1))) void*)(gp), \
    (__attribute__((address_space(3))) void*)(lp), 16, 0, 0)

__device__ __forceinline__ float sigf(float x){
  return 1.0f/(1.0f + exp2f(x * -1.44269504f));
}
__device__ __forceinline__ float tanh_fast(float x){
  return 2.0f/(1.0f + exp2f(x * -2.88539008f)) - 1.0f;
}

// ------------- convert fp32 -> fp16 (emb, Ufw, Uiou, Wiou) + zero rep -------
__global__ __launch_bounds__(256) void convert_all(const float* __restrict__ emb,
    const float* __restrict__ Ufw, const float* __restrict__ Uiou,
    const float* __restrict__ Wiou, h16* __restrict__ emb16,
    h16* __restrict__ W16, h16* __restrict__ Wx16, float* __restrict__ rep){
  if (blockIdx.x < 64)
    ((float4*)rep)[blockIdx.x*256 + threadIdx.x] = make_float4(0.f,0.f,0.f,0.f);
  const size_t i0 = ((size_t)blockIdx.x*256 + threadIdx.x)*8;
  const float* src; h16* dst; size_t off;
  if (i0 < 8192000UL){ src = emb;  dst = emb16;       off = i0; }
  else if (i0 < 8257536UL){ src = Ufw;  dst = W16;        off = i0 - 8192000UL; }
  else if (i0 < 8454144UL){ src = Uiou; dst = W16+65536;  off = i0 - 8257536UL; }
  else               { src = Wiou; dst = Wx16;       off = i0 - 8454144UL; }
  const float4 v0 = *(const float4*)&src[off];
  const float4 v1 = *(const float4*)&src[off+4];
  f16x8 o;
  o[0]=(h16)v0.x; o[1]=(h16)v0.y; o[2]=(h16)v0.z; o[3]=(h16)v0.w;
  o[4]=(h16)v1.x; o[5]=(h16)v1.y; o[6]=(h16)v1.z; o[7]=(h16)v1.w;
  *(f16x8*)&dst[off] = o;
}

// ------------- swizzle W16 into MFMA fragment order -------------
// Wfrag[(((cb*8 + kc)*16 + f)*64 + lane)*8 + j]
//   = W16[(g*256 + cb*64 + cf*16 + (lane&15)) * 256 + kc*32 + (lane>>4)*8 + j]
// f = g*4 + cf (g = gate 0..3, cf = 16-col frag 0..3 within the 64-col group)
__global__ __launch_bounds__(256) void swizzle_w(const h16* __restrict__ W16,
    h16* __restrict__ Wfrag){
  const int tid = blockIdx.x*256 + threadIdx.x;   // 0..65535
  const int lane = tid & 63;
  const int f    = (tid >> 6) & 15;
  const int kc   = (tid >> 10) & 7;
  const int cb   = tid >> 13;
  const int g = f >> 2, cf = f & 3;
  const int row = g*256 + cb*64 + cf*16 + (lane & 15);
  const int col = kc*32 + (lane >> 4)*8;
  const f16x8 v = *(const f16x8*)&W16[(size_t)row*256 + col];
  *(f16x8*)&Wfrag[(size_t)tid*8] = v;
}

// ------------- WxV = emb16 @ Wx16^T : M=32000, N=768, K=256 (MFMA) -------------
__global__ __launch_bounds__(256) void wxv_mfma(const h16* __restrict__ emb16,
    const h16* __restrict__ Wx16, h16* __restrict__ WxV){
  __shared__ h16 As[64*40];
  __shared__ h16 Bs[64*40];
  const int t = threadIdx.x, lane = t & 63, wave = t >> 6;
  const int q = lane >> 4, li = lane & 15;
  const int waveR = wave & 1, waveC = wave >> 1;
  const int bm = blockIdx.x*64, bn = blockIdx.y*64;
  const size_t aAddr = ((size_t)(bm + (t>>2)))*256 + (t&3)*8;
  const size_t bAddr = ((size_t)(bn + (t>>2)))*256 + (t&3)*8;
  const int ldsOff = (t>>2)*40 + (t&3)*8;
  f32x4 acc[2][2] = {};
  for (int k0 = 0; k0 < 256; k0 += 32){
    const f16x8 a = *(const f16x8*)&emb16[aAddr + k0];
    const f16x8 b = *(const f16x8*)&Wx16[bAddr + k0];
    __syncthreads();
    *(f16x8*)&As[ldsOff] = a;
    *(f16x8*)&Bs[ldsOff] = b;
    __syncthreads();
    #pragma unroll
    for (int rt=0; rt<2; ++rt){
      const f16x8 av = *(const f16x8*)&As[(waveR*32 + rt*16 + li)*40 + q*8];
      #pragma unroll
      for (int ct=0; ct<2; ++ct){
        const f16x8 bv = *(const f16x8*)&Bs[(waveC*32 + ct*16 + li)*40 + q*8];
        acc[rt][ct] = __builtin_amdgcn_mfma_f32_16x16x32_f16(av, bv, acc[rt][ct], 0,0,0);
      }
    }
  }
  #pragma unroll
  for (int rt=0; rt<2; ++rt)
    #pragma unroll
    for (int ct=0; ct<2; ++ct){
      const int col = bn + waveC*32 + ct*16 + li;
      #pragma unroll
      for (int reg=0; reg<4; ++reg){
        const int row = bm + waveR*32 + rt*16 + q*4 + reg;
        WxV[(size_t)row*768 + col] = (h16)acc[rt][ct][reg];
      }
    }
}

// ------------- leaves: gather WxV, cell, write h (c NOT stored) -------------
__global__ __launch_bounds__(256) void leaf_kernel(const int* __restrict__ t1,
    const int* __restrict__ t2, const h16* __restrict__ WxV,
    const float* __restrict__ biou, h16* __restrict__ leafH){
  const int r = blockIdx.y, jg = blockIdx.x, k = threadIdx.x;
  const int* tp = (r < 128) ? t1 : t2;
  const int b = r & 127;
  const float bi = biou[k], bo = biou[256+k], bu = biou[512+k];
  #pragma unroll
  for (int jj=0; jj<8; ++jj){
    const int leafIdx = jg*8 + jj;
    const size_t v = (size_t)tp[b*NTREE + 511 + leafIdx];
    const float vi = (float)WxV[v*768 + k] + bi;
    const float vo = (float)WxV[v*768 + 256 + k] + bo;
    const float vu = (float)WxV[v*768 + 512 + k] + bu;
    const float c = sigf(vi) * tanh_fast(vu);
    const float h = sigf(vo) * tanh_fast(c);
    leafH[((size_t)r*512 + leafIdx)*HS + k] = (h16)h;
  }
}

// ------------- DMA-staged fused MFMA level kernel (contiguous B-DMA) -------
// ldsA[R=4][kc=8][lane][16B]=32KB staged once (scattered source, one-time).
// ldsB[f=16][lane][16B]=16KB staged per kc from Wfrag: each DMA16 reads a
// CONTIGUOUS 1KB (lane l -> +l*16B) and lands in frag-order. 2-barrier loop.
__global__ __launch_bounds__(256,3) void level_mfma(
    const h16* __restrict__ hChild, const h16* __restrict__ cChild,
    const h16* __restrict__ Wfrag,   // [cb=4][kc=8][f=16][lane=64][8]
    const h16* __restrict__ WxV,
    const int* __restrict__ t1, const int* __restrict__ t2,
    const float* __restrict__ biou, const float* __restrict__ Ufb,
    h16* __restrict__ hUp, h16* __restrict__ cPar,
    int log2n, int leafLvl, int cbN){
  const int n = 1 << log2n;
  const int mask2 = 2*n - 1;
  const int strideR = leafLvl ? 512 : 511;
  const int childBase = leafLvl ? 0 : mask2;
  __shared__ h16 ldsA[4*8*64*8];   // 32 KB
  __shared__ h16 ldsB[16*64*8];    // 16 KB
  const int t = threadIdx.x, w = t >> 6, l = t & 63;
  const int q = l >> 4, li = l & 15;
  const int waveR = w & 1, waveC = w >> 1;
  const int bx = blockIdx.x;

  // ---- stage A once: wave w stages rowFrag R=w, kc=0..7 (frag-order) ----
  {
    const int grow = bx*64 + w*16 + li;
    const int rr = grow >> (log2n + 1);
    const size_t abase = ((size_t)rr*strideR + childBase + (grow & mask2))*256;
    #pragma unroll
    for (int kc=0; kc<8; ++kc)
      DMA16(hChild + abase + kc*32 + q*8, &ldsA[(w*8 + kc)*512]);
  }

  for (int cb=0; cb<cbN; ++cb){
    const int cbi = blockIdx.y*cbN + cb;            // 64-col group 0..3
    const int colBase = cbi*64;
    const h16* wfBase = Wfrag + (size_t)cbi*8*16*512 + l*8;

    f32x4 acc[4][2][2] = {};   // [gate f,i,o,u][rt][ct]
    for (int kc=0; kc<8; ++kc){
      // stage B chunk kc: wave w stages fragments f = w*4 .. w*4+3,
      // each a CONTIGUOUS 1KB read (lane l -> +l*16B).
      #pragma unroll
      for (int i=0; i<4; ++i){
        const int f = w*4 + i;
        DMA16(wfBase + ((size_t)kc*16 + f)*512, &ldsB[f*512]);
      }
      __syncthreads();   // drain DMA (A on first pass, B every pass)
      f16x8 aF[2], bF[4][2];
      #pragma unroll
      for (int rt=0; rt<2; ++rt)
        aF[rt] = *(const f16x8*)&ldsA[(((waveR*2 + rt)*8 + kc)*64 + l)*8];
      #pragma unroll
      for (int g=0; g<4; ++g)
        #pragma unroll
        for (int ct=0; ct<2; ++ct)
          bF[g][ct] = *(const f16x8*)&ldsB[((g*4 + waveC*2 + ct)*64 + l)*8];
      #pragma unroll
      for (int g=0; g<4; ++g)
        #pragma unroll
        for (int rt=0; rt<2; ++rt)
          #pragma unroll
          for (int ct=0; ct<2; ++ct)
            acc[g][rt][ct] = __builtin_amdgcn_mfma_f32_16x16x32_f16(
                aF[rt], bF[g][ct], acc[g][rt][ct], 0,0,0);
      __syncthreads();   // all ldsB reads done before next kc's DMA overwrites
    }

    // ---- epilogue (all lane-local; sibling pairs = adjacent C regs) ----
    #pragma unroll
    for (int ct=0; ct<2; ++ct){
      const int c = colBase + waveC*32 + ct*16 + li;
      const float fb  = Ufb[c];
      const float bi_ = biou[c], bo_ = biou[256+c], bu_ = biou[512+c];
      #pragma unroll
      for (int rt=0; rt<2; ++rt){
        #pragma unroll
        for (int pp=0; pp<2; ++pp){
          const int crel = waveR*32 + rt*16 + q*4 + 2*pp;  // even child row (rel)
          const int m = bx*32 + (crel >> 1);               // global parent index
          const int rr2 = m >> log2n;
          const int jn = m & (n - 1);
          const float fl = sigf(acc[0][rt][ct][2*pp]   + fb);
          const float fr = sigf(acc[0][rt][ct][2*pp+1] + fb);
          const float iv = acc[1][rt][ct][2*pp] + acc[1][rt][ct][2*pp+1] + bi_;
          const float ov = acc[2][rt][ct][2*pp] + acc[2][rt][ct][2*pp+1] + bo_;
          const float uv = acc[3][rt][ct][2*pp] + acc[3][rt][ct][2*pp+1] + bu_;
          float cl, cr;
          if (leafLvl){
            const int* tp = (rr2 < 128) ? t1 : t2;
            const int b = rr2 & 127;
            const size_t vl = (size_t)tp[b*NTREE + 511 + 2*jn];
            const size_t vr = (size_t)tp[b*NTREE + 512 + 2*jn];
            cl = sigf((float)WxV[vl*768 + c] + bi_) * tanh_fast((float)WxV[vl*768 + 512 + c] + bu_);
            cr = sigf((float)WxV[vr*768 + c] + bi_) * tanh_fast((float)WxV[vr*768 + 512 + c] + bu_);
          } else {
            const int cgl = bx*64 + crel;
            cl = (float)cChild[(size_t)cgl*256 + c];
            cr = (float)cChild[(size_t)(cgl+1)*256 + c];
          }
          const float cnew = sigf(iv)*tanh_fast(uv) + fl*cl + fr*cr;
          const float hnew = sigf(ov)*tanh_fast(cnew);
          hUp [((size_t)rr2*511 + (n-1) + jn)*256 + c] = (h16)hnew;
          cPar[((size_t)m)*256 + c] = (h16)cnew;
        }
      }
    }
  }
}

// ------------- rep accumulation -------------
__global__ __launch_bounds__(256) void rep_accum(const h16* __restrict__ H,
    float* __restrict__ rep, int nrows, int chunk){
  const int r = blockIdx.y, k = threadIdx.x;
  const int n0 = blockIdx.x * chunk;
  int n1 = n0 + chunk; if (n1 > nrows) n1 = nrows;
  float s = 0.f;
  for (int nd = n0; nd < n1; ++nd)
    s += (float)H[((size_t)r*nrows + nd)*HS + k];
  atomicAdd(&rep[r*HS + k], s);
}

// ------------- classifier -------------
__global__ __launch_bounds__(256) void cls_kernel(const float* __restrict__ rep,
    const float* __restrict__ clsw, const float* __restrict__ clsb,
    float* __restrict__ out){
  const int b = blockIdx.x, k = threadIdx.x;
  const float d = fabsf(rep[b*HS + k] - rep[(128+b)*HS + k]) * (1.0f/1023.0f);
  __shared__ float r0[256], r1[256];
  r0[k] = d * clsw[k];
  r1[k] = d * clsw[HS + k];
  __syncthreads();
  for (int off = 128; off > 0; off >>= 1){
    if (k < off){ r0[k] += r0[k+off]; r1[k] += r1[k+off]; }
    __syncthreads();
  }
  if (k == 0){
    out[b*2 + 0] = r0[0] + clsb[0];
    out[b*2 + 1] = r1[0] + clsb[1];
  }
}

extern "C" void kernel_launch(void* const* d_in, const int* in_sizes, int n_in,
                              void* d_out, int out_size, void* d_ws, size_t ws_size,
                              hipStream_t stream){
  const int*   types1 = (const int*)d_in[0];
  const int*   types2 = (const int*)d_in[1];
  const float* emb    = (const float*)d_in[2];
  const float* Wiou   = (const float*)d_in[3];
  const float* Uiou   = (const float*)d_in[4];
  const float* biou   = (const float*)d_in[5];
  const float* Ufw    = (const float*)d_in[6];
  const float* Ufb    = (const float*)d_in[7];
  const float* clsw   = (const float*)d_in[8];
  const float* clsb   = (const float*)d_in[9];
  float* out = (float*)d_out;

  h16* WxV   = (h16*)d_ws;                        // 24,576,000
  h16* leafH = WxV   + 24576000UL;                // 33,554,432
  h16* hUp   = leafH + 33554432UL;                // 33,488,896
  h16* cA    = hUp   + 33488896UL;                // 16,777,216
  h16* cB    = cA    + 16777216UL;                //  8,388,608
  h16* emb16 = cB;                                //  8,192,000 (overlay on cB)
  h16* Wx16  = cB + 8192000UL;                    //    196,608 (overlay on cB)
  float* rep = (float*)(cB + 8388608UL);          //     65,536 fp32
  h16* W16   = (h16*)(rep + 65536UL);             //    262,144
  h16* Wfrag = W16 + 262144UL;                    //    524,288 (1 MB)

  convert_all<<<4224, 256, 0, stream>>>(emb, Ufw, Uiou, Wiou, emb16, W16, Wx16, rep);
  swizzle_w<<<256, 256, 0, stream>>>(W16, Wfrag);
  wxv_mfma<<<dim3(500,12), 256, 0, stream>>>(emb16, Wx16, WxV);
  leaf_kernel<<<dim3(64, B2), 256, 0, stream>>>(types1, types2, WxV, biou, leafH);

  const h16* cprev = nullptr;
  for (int lvl = 8; lvl >= 0; --lvl){
    const int children = 512 << lvl;        // B2 * 2n
    const int cbN = (lvl >= 6) ? 4 : 1;     // big levels: y=1, col loop in-block
    h16* cout = ((8 - lvl) & 1) ? cB : cA;
    level_mfma<<<dim3(children/64, 4/cbN), 256, 0, stream>>>(
        (lvl == 8) ? leafH : hUp, cprev, Wfrag, WxV, types1, types2,
        biou, Ufb, hUp, cout, lvl, (lvl == 8) ? 1 : 0, cbN);
    cprev = cout;
  }
  rep_accum<<<dim3(4, B2), 256, 0, stream>>>(leafH, rep, 512, 128);
  rep_accum<<<dim3(4, B2), 256, 0, stream>>>(hUp,   rep, 511, 128);
  cls_kernel<<<128, 256, 0, stream>>>(rep, clsw, clsb, out);
}

// Round 11
// 627.306 us; speedup vs baseline: 1.9414x; 1.0456x over previous
//
#include <hip/hip_runtime.h>
#include <math.h>

// TreeLSTM MI355X — R11: R10 + (1) leafC materialization (runtime ws_size
// branch; kills leaf-epilogue transcendental recompute + WxV gathers),
// (2) kc-loop reorder (reads->barrier->DMA->MFMA->barrier: both drains cheap),
// (3) leaf rep-sum folded into leaf_kernel.
// ws: 235.4 MB base; +67.1 MB leafC if ws_size >= 303 MB.

typedef _Float16 h16;
typedef h16 f16x8 __attribute__((ext_vector_type(8)));
typedef float f32x4 __attribute__((ext_vector_type(4)));

#define HS 256
#define NTREE 1023
#define B2 256

#define DMA16(gp, lp) __builtin_amdgcn_global_load_lds( \
    (const __attribute__((address_space(1))) void*)(gp), \
    (__attribute__((address_space(3))) void*)(lp), 16, 0, 0)

__device__ __forceinline__ float sigf(float x){
  return 1.0f/(1.0f + exp2f(x * -1.44269504f));
}
__device__ __forceinline__ float tanh_fast(float x){
  return 2.0f/(1.0f + exp2f(x * -2.88539008f)) - 1.0f;
}

// ------------- convert fp32 -> fp16 (emb, Ufw, Uiou, Wiou) + zero rep -------
__global__ __launch_bounds__(256) void convert_all(const float* __restrict__ emb,
    const float* __restrict__ Ufw, const float* __restrict__ Uiou,
    const float* __restrict__ Wiou, h16* __restrict__ emb16,
    h16* __restrict__ W16, h16* __restrict__ Wx16, float* __restrict__ rep){
  if (blockIdx.x < 64)
    ((float4*)rep)[blockIdx.x*256 + threadIdx.x] = make_float4(0.f,0.f,0.f,0.f);
  const size_t i0 = ((size_t)blockIdx.x*256 + threadIdx.x)*8;
  const float* src; h16* dst; size_t off;
  if (i0 < 8192000UL){ src = emb;  dst = emb16;       off = i0; }
  else if (i0 < 8257536UL){ src = Ufw;  dst = W16;        off = i0 - 8192000UL; }
  else if (i0 < 8454144UL){ src = Uiou; dst = W16+65536;  off = i0 - 8257536UL; }
  else               { src = Wiou; dst = Wx16;       off = i0 - 8454144UL; }
  const float4 v0 = *(const float4*)&src[off];
  const float4 v1 = *(const float4*)&src[off+4];
  f16x8 o;
  o[0]=(h16)v0.x; o[1]=(h16)v0.y; o[2]=(h16)v0.z; o[3]=(h16)v0.w;
  o[4]=(h16)v1.x; o[5]=(h16)v1.y; o[6]=(h16)v1.z; o[7]=(h16)v1.w;
  *(f16x8*)&dst[off] = o;
}

// ------------- swizzle W16 into MFMA fragment order -------------
__global__ __launch_bounds__(256) void swizzle_w(const h16* __restrict__ W16,
    h16* __restrict__ Wfrag){
  const int tid = blockIdx.x*256 + threadIdx.x;   // 0..65535
  const int lane = tid & 63;
  const int f    = (tid >> 6) & 15;
  const int kc   = (tid >> 10) & 7;
  const int cb   = tid >> 13;
  const int g = f >> 2, cf = f & 3;
  const int row = g*256 + cb*64 + cf*16 + (lane & 15);
  const int col = kc*32 + (lane >> 4)*8;
  const f16x8 v = *(const f16x8*)&W16[(size_t)row*256 + col];
  *(f16x8*)&Wfrag[(size_t)tid*8] = v;
}

// ------------- WxV = emb16 @ Wx16^T : M=32000, N=768, K=256 (MFMA) -------------
__global__ __launch_bounds__(256) void wxv_mfma(const h16* __restrict__ emb16,
    const h16* __restrict__ Wx16, h16* __restrict__ WxV){
  __shared__ h16 As[64*40];
  __shared__ h16 Bs[64*40];
  const int t = threadIdx.x, lane = t & 63, wave = t >> 6;
  const int q = lane >> 4, li = lane & 15;
  const int waveR = wave & 1, waveC = wave >> 1;
  const int bm = blockIdx.x*64, bn = blockIdx.y*64;
  const size_t aAddr = ((size_t)(bm + (t>>2)))*256 + (t&3)*8;
  const size_t bAddr = ((size_t)(bn + (t>>2)))*256 + (t&3)*8;
  const int ldsOff = (t>>2)*40 + (t&3)*8;
  f32x4 acc[2][2] = {};
  for (int k0 = 0; k0 < 256; k0 += 32){
    const f16x8 a = *(const f16x8*)&emb16[aAddr + k0];
    const f16x8 b = *(const f16x8*)&Wx16[bAddr + k0];
    __syncthreads();
    *(f16x8*)&As[ldsOff] = a;
    *(f16x8*)&Bs[ldsOff] = b;
    __syncthreads();
    #pragma unroll
    for (int rt=0; rt<2; ++rt){
      const f16x8 av = *(const f16x8*)&As[(waveR*32 + rt*16 + li)*40 + q*8];
      #pragma unroll
      for (int ct=0; ct<2; ++ct){
        const f16x8 bv = *(const f16x8*)&Bs[(waveC*32 + ct*16 + li)*40 + q*8];
        acc[rt][ct] = __builtin_amdgcn_mfma_f32_16x16x32_f16(av, bv, acc[rt][ct], 0,0,0);
      }
    }
  }
  #pragma unroll
  for (int rt=0; rt<2; ++rt)
    #pragma unroll
    for (int ct=0; ct<2; ++ct){
      const int col = bn + waveC*32 + ct*16 + li;
      #pragma unroll
      for (int reg=0; reg<4; ++reg){
        const int row = bm + waveR*32 + rt*16 + q*4 + reg;
        WxV[(size_t)row*768 + col] = (h16)acc[rt][ct][reg];
      }
    }
}

// ------------- leaves: gather WxV, cell, write h (+opt c), fold rep --------
// grid (8, 256): thread (jg,r,k) covers 64 leaves, one rep atomic at the end.
__global__ __launch_bounds__(256) void leaf_kernel(const int* __restrict__ t1,
    const int* __restrict__ t2, const h16* __restrict__ WxV,
    const float* __restrict__ biou, h16* __restrict__ leafH,
    h16* __restrict__ leafC, int haveLeafC, float* __restrict__ rep){
  const int r = blockIdx.y, jg = blockIdx.x, k = threadIdx.x;
  const int* tp = (r < 128) ? t1 : t2;
  const int b = r & 127;
  const float bi = biou[k], bo = biou[256+k], bu = biou[512+k];
  float s = 0.f;
  for (int jj=0; jj<64; ++jj){
    const int leafIdx = jg*64 + jj;
    const size_t v = (size_t)tp[b*NTREE + 511 + leafIdx];
    const float vi = (float)WxV[v*768 + k] + bi;
    const float vo = (float)WxV[v*768 + 256 + k] + bo;
    const float vu = (float)WxV[v*768 + 512 + k] + bu;
    const float c = sigf(vi) * tanh_fast(vu);
    const float h = sigf(vo) * tanh_fast(c);
    const size_t o = ((size_t)r*512 + leafIdx)*HS + k;
    leafH[o] = (h16)h;
    if (haveLeafC) leafC[o] = (h16)c;
    s += h;
  }
  atomicAdd(&rep[r*HS + k], s);
}

// ------------- DMA-staged fused MFMA level kernel -------------
// ldsA staged once; ldsB per kc from Wfrag via contiguous 1KB DMA16.
// kc loop: reads -> barrier(cheap) -> DMA(kc+1) -> MFMA -> barrier(drain
// hidden behind MFMA). Epilogue: cChild path (incl. lvl-8 when leafC
// materialized) or WxV-gather fallback.
__global__ __launch_bounds__(256,3) void level_mfma(
    const h16* __restrict__ hChild, const h16* __restrict__ cChild,
    const h16* __restrict__ Wfrag,   // [cb=4][kc=8][f=16][lane=64][8]
    const h16* __restrict__ WxV,
    const int* __restrict__ t1, const int* __restrict__ t2,
    const float* __restrict__ biou, const float* __restrict__ Ufb,
    h16* __restrict__ hUp, h16* __restrict__ cPar,
    int log2n, int leafLvl, int cbN, int useCc){
  const int n = 1 << log2n;
  const int mask2 = 2*n - 1;
  const int strideR = leafLvl ? 512 : 511;
  const int childBase = leafLvl ? 0 : mask2;
  const int gatherLeaf = leafLvl && !useCc;
  __shared__ h16 ldsA[4*8*64*8];   // 32 KB
  __shared__ h16 ldsB[16*64*8];    // 16 KB
  const int t = threadIdx.x, w = t >> 6, l = t & 63;
  const int q = l >> 4, li = l & 15;
  const int waveR = w & 1, waveC = w >> 1;
  const int bx = blockIdx.x;

  // ---- stage A once: wave w stages rowFrag R=w, kc=0..7 (frag-order) ----
  {
    const int grow = bx*64 + w*16 + li;
    const int rr = grow >> (log2n + 1);
    const size_t abase = ((size_t)rr*strideR + childBase + (grow & mask2))*256;
    #pragma unroll
    for (int kc=0; kc<8; ++kc)
      DMA16(hChild + abase + kc*32 + q*8, &ldsA[(w*8 + kc)*512]);
  }

  for (int cb=0; cb<cbN; ++cb){
    const int cbi = blockIdx.y*cbN + cb;            // 64-col group 0..3
    const int colBase = cbi*64;
    const h16* wfBase = Wfrag + (size_t)cbi*8*16*512 + l*8;

    // prologue: DMA B(kc=0)
    #pragma unroll
    for (int i=0; i<4; ++i)
      DMA16(wfBase + ((size_t)(w*4 + i))*512, &ldsB[(w*4 + i)*512]);
    __syncthreads();   // drains A-DMA (cb==0) + B(0) + prior epilogue stores

    f32x4 acc[4][2][2] = {};   // [gate f,i,o,u][rt][ct]
    #pragma unroll
    for (int kc=0; kc<8; ++kc){
      // reads of ldsB(kc) + ldsA(kc) into regs
      f16x8 aF[2], bF[4][2];
      #pragma unroll
      for (int rt=0; rt<2; ++rt)
        aF[rt] = *(const f16x8*)&ldsA[(((waveR*2 + rt)*8 + kc)*64 + l)*8];
      #pragma unroll
      for (int g=0; g<4; ++g)
        #pragma unroll
        for (int ct=0; ct<2; ++ct)
          bF[g][ct] = *(const f16x8*)&ldsB[((g*4 + waveC*2 + ct)*64 + l)*8];
      __syncthreads();   // all reads done; no fresh vmem to drain (cheap)
      if (kc < 7){
        #pragma unroll
        for (int i=0; i<4; ++i)
          DMA16(wfBase + ((size_t)(kc+1)*16 + w*4 + i)*512,
                &ldsB[(w*4 + i)*512]);
      }
      #pragma unroll
      for (int g=0; g<4; ++g)
        #pragma unroll
        for (int rt=0; rt<2; ++rt)
          #pragma unroll
          for (int ct=0; ct<2; ++ct)
            acc[g][rt][ct] = __builtin_amdgcn_mfma_f32_16x16x32_f16(
                aF[rt], bF[g][ct], acc[g][rt][ct], 0,0,0);
      __syncthreads();   // drains B(kc+1) DMA — issued before the MFMA block
    }

    // ---- epilogue (all lane-local; sibling pairs = adjacent C regs) ----
    #pragma unroll
    for (int ct=0; ct<2; ++ct){
      const int c = colBase + waveC*32 + ct*16 + li;
      const float fb  = Ufb[c];
      const float bi_ = biou[c], bo_ = biou[256+c], bu_ = biou[512+c];
      #pragma unroll
      for (int rt=0; rt<2; ++rt){
        #pragma unroll
        for (int pp=0; pp<2; ++pp){
          const int crel = waveR*32 + rt*16 + q*4 + 2*pp;  // even child row (rel)
          const int m = bx*32 + (crel >> 1);               // global parent index
          const int rr2 = m >> log2n;
          const int jn = m & (n - 1);
          const float fl = sigf(acc[0][rt][ct][2*pp]   + fb);
          const float fr = sigf(acc[0][rt][ct][2*pp+1] + fb);
          const float iv = acc[1][rt][ct][2*pp] + acc[1][rt][ct][2*pp+1] + bi_;
          const float ov = acc[2][rt][ct][2*pp] + acc[2][rt][ct][2*pp+1] + bo_;
          const float uv = acc[3][rt][ct][2*pp] + acc[3][rt][ct][2*pp+1] + bu_;
          float cl, cr;
          if (gatherLeaf){
            const int* tp = (rr2 < 128) ? t1 : t2;
            const int b = rr2 & 127;
            const size_t vl = (size_t)tp[b*NTREE + 511 + 2*jn];
            const size_t vr = (size_t)tp[b*NTREE + 512 + 2*jn];
            cl = sigf((float)WxV[vl*768 + c] + bi_) * tanh_fast((float)WxV[vl*768 + 512 + c] + bu_);
            cr = sigf((float)WxV[vr*768 + c] + bi_) * tanh_fast((float)WxV[vr*768 + 512 + c] + bu_);
          } else {
            const int cgl = bx*64 + crel;
            cl = (float)cChild[(size_t)cgl*256 + c];
            cr = (float)cChild[(size_t)(cgl+1)*256 + c];
          }
          const float cnew = sigf(iv)*tanh_fast(uv) + fl*cl + fr*cr;
          const float hnew = sigf(ov)*tanh_fast(cnew);
          hUp [((size_t)rr2*511 + (n-1) + jn)*256 + c] = (h16)hnew;
          cPar[((size_t)m)*256 + c] = (h16)cnew;
        }
      }
    }
  }
}

// ------------- rep accumulation (internal nodes, hUp) -------------
__global__ __launch_bounds__(256) void rep_accum(const h16* __restrict__ H,
    float* __restrict__ rep, int nrows, int chunk){
  const int r = blockIdx.y, k = threadIdx.x;
  const int n0 = blockIdx.x * chunk;
  int n1 = n0 + chunk; if (n1 > nrows) n1 = nrows;
  float s = 0.f;
  for (int nd = n0; nd < n1; ++nd)
    s += (float)H[((size_t)r*nrows + nd)*HS + k];
  atomicAdd(&rep[r*HS + k], s);
}

// ------------- classifier -------------
__global__ __launch_bounds__(256) void cls_kernel(const float* __restrict__ rep,
    const float* __restrict__ clsw, const float* __restrict__ clsb,
    float* __restrict__ out){
  const int b = blockIdx.x, k = threadIdx.x;
  const float d = fabsf(rep[b*HS + k] - rep[(128+b)*HS + k]) * (1.0f/1023.0f);
  __shared__ float r0[256], r1[256];
  r0[k] = d * clsw[k];
  r1[k] = d * clsw[HS + k];
  __syncthreads();
  for (int off = 128; off > 0; off >>= 1){
    if (k < off){ r0[k] += r0[k+off]; r1[k] += r1[k+off]; }
    __syncthreads();
  }
  if (k == 0){
    out[b*2 + 0] = r0[0] + clsb[0];
    out[b*2 + 1] = r1[0] + clsb[1];
  }
}

extern "C" void kernel_launch(void* const* d_in, const int* in_sizes, int n_in,
                              void* d_out, int out_size, void* d_ws, size_t ws_size,
                              hipStream_t stream){
  const int*   types1 = (const int*)d_in[0];
  const int*   types2 = (const int*)d_in[1];
  const float* emb    = (const float*)d_in[2];
  const float* Wiou   = (const float*)d_in[3];
  const float* Uiou   = (const float*)d_in[4];
  const float* biou   = (const float*)d_in[5];
  const float* Ufw    = (const float*)d_in[6];
  const float* Ufb    = (const float*)d_in[7];
  const float* clsw   = (const float*)d_in[8];
  const float* clsb   = (const float*)d_in[9];
  float* out = (float*)d_out;

  h16* WxV   = (h16*)d_ws;                        // 24,576,000
  h16* leafH = WxV   + 24576000UL;                // 33,554,432
  h16* hUp   = leafH + 33554432UL;                // 33,488,896
  h16* cA    = hUp   + 33488896UL;                // 16,777,216
  h16* cB    = cA    + 16777216UL;                //  8,388,608
  h16* emb16 = cB;                                //  8,192,000 (overlay on cB)
  h16* Wx16  = cB + 8192000UL;                    //    196,608 (overlay on cB)
  float* rep = (float*)(cB + 8388608UL);          //     65,536 fp32
  h16* W16   = (h16*)(rep + 65536UL);             //    262,144
  h16* Wfrag = W16 + 262144UL;                    //    524,288 (1 MB)
  h16* leafC = Wfrag + 524288UL;                  // 33,554,432 (optional, 67 MB)
  // base footprint ends at leafC: 235,405,312 B; +leafC -> 302,514,176 B
  const int haveLeafC = (ws_size >= 302600000UL) ? 1 : 0;

  convert_all<<<4224, 256, 0, stream>>>(emb, Ufw, Uiou, Wiou, emb16, W16, Wx16, rep);
  swizzle_w<<<256, 256, 0, stream>>>(W16, Wfrag);
  wxv_mfma<<<dim3(500,12), 256, 0, stream>>>(emb16, Wx16, WxV);
  leaf_kernel<<<dim3(8, B2), 256, 0, stream>>>(types1, types2, WxV, biou,
                                               leafH, leafC, haveLeafC, rep);

  const h16* cprev = nullptr;
  for (int lvl = 8; lvl >= 0; --lvl){
    const int children = 512 << lvl;        // B2 * 2n
    const int cbN = (lvl >= 6) ? 4 : 1;     // big levels: y=1, col loop in-block
    h16* cout = ((8 - lvl) & 1) ? cB : cA;
    const h16* cin = (lvl == 8) ? (haveLeafC ? leafC : nullptr) : cprev;
    level_mfma<<<dim3(children/64, 4/cbN), 256, 0, stream>>>(
        (lvl == 8) ? leafH : hUp, cin, Wfrag, WxV, types1, types2,
        biou, Ufb, hUp, cout, lvl, (lvl == 8) ? 1 : 0, cbN,
        (lvl == 8) ? haveLeafC : 1);
    cprev = cout;
  }
  rep_accum<<<dim3(4, B2), 256, 0, stream>>>(hUp, rep, 511, 128);
  cls_kernel<<<128, 256, 0, stream>>>(rep, clsw, clsb, out);
}

// Round 12
// 553.680 us; speedup vs baseline: 2.1996x; 1.1330x over previous
//
#include <hip/hip_runtime.h>
#include <math.h>

// TreeLSTM MI355X — R12: R11 + fast reciprocal (v_rcp_f32) in sigf/tanh.
// R11 post-mortem: VALUBusy 65% traced to full IEEE fp32 divide sequences
// (~12 ops each) in the 33.5M sigmoid/tanh cell evaluations. 1-ulp
// __builtin_amdgcn_rcpf replaces them (numerically invisible vs fp16 storage).
// ws: 235.4 MB base; +67.1 MB leafC if ws_size >= 303 MB.

typedef _Float16 h16;
typedef h16 f16x8 __attribute__((ext_vector_type(8)));
typedef float f32x4 __attribute__((ext_vector_type(4)));

#define HS 256
#define NTREE 1023
#define B2 256

#define DMA16(gp, lp) __builtin_amdgcn_global_load_lds( \
    (const __attribute__((address_space(1))) void*)(gp), \
    (__attribute__((address_space(3))) void*)(lp), 16, 0, 0)

__device__ __forceinline__ float sigf(float x){
  return __builtin_amdgcn_rcpf(1.0f + exp2f(x * -1.44269504f));
}
__device__ __forceinline__ float tanh_fast(float x){
  return 2.0f*__builtin_amdgcn_rcpf(1.0f + exp2f(x * -2.88539008f)) - 1.0f;
}

// ------------- convert fp32 -> fp16 (emb, Ufw, Uiou, Wiou) + zero rep -------
__global__ __launch_bounds__(256) void convert_all(const float* __restrict__ emb,
    const float* __restrict__ Ufw, const float* __restrict__ Uiou,
    const float* __restrict__ Wiou, h16* __restrict__ emb16,
    h16* __restrict__ W16, h16* __restrict__ Wx16, float* __restrict__ rep){
  if (blockIdx.x < 64)
    ((float4*)rep)[blockIdx.x*256 + threadIdx.x] = make_float4(0.f,0.f,0.f,0.f);
  const size_t i0 = ((size_t)blockIdx.x*256 + threadIdx.x)*8;
  const float* src; h16* dst; size_t off;
  if (i0 < 8192000UL){ src = emb;  dst = emb16;       off = i0; }
  else if (i0 < 8257536UL){ src = Ufw;  dst = W16;        off = i0 - 8192000UL; }
  else if (i0 < 8454144UL){ src = Uiou; dst = W16+65536;  off = i0 - 8257536UL; }
  else               { src = Wiou; dst = Wx16;       off = i0 - 8454144UL; }
  const float4 v0 = *(const float4*)&src[off];
  const float4 v1 = *(const float4*)&src[off+4];
  f16x8 o;
  o[0]=(h16)v0.x; o[1]=(h16)v0.y; o[2]=(h16)v0.z; o[3]=(h16)v0.w;
  o[4]=(h16)v1.x; o[5]=(h16)v1.y; o[6]=(h16)v1.z; o[7]=(h16)v1.w;
  *(f16x8*)&dst[off] = o;
}

// ------------- swizzle W16 into MFMA fragment order -------------
__global__ __launch_bounds__(256) void swizzle_w(const h16* __restrict__ W16,
    h16* __restrict__ Wfrag){
  const int tid = blockIdx.x*256 + threadIdx.x;   // 0..65535
  const int lane = tid & 63;
  const int f    = (tid >> 6) & 15;
  const int kc   = (tid >> 10) & 7;
  const int cb   = tid >> 13;
  const int g = f >> 2, cf = f & 3;
  const int row = g*256 + cb*64 + cf*16 + (lane & 15);
  const int col = kc*32 + (lane >> 4)*8;
  const f16x8 v = *(const f16x8*)&W16[(size_t)row*256 + col];
  *(f16x8*)&Wfrag[(size_t)tid*8] = v;
}

// ------------- WxV = emb16 @ Wx16^T : M=32000, N=768, K=256 (MFMA) -------------
__global__ __launch_bounds__(256) void wxv_mfma(const h16* __restrict__ emb16,
    const h16* __restrict__ Wx16, h16* __restrict__ WxV){
  __shared__ h16 As[64*40];
  __shared__ h16 Bs[64*40];
  const int t = threadIdx.x, lane = t & 63, wave = t >> 6;
  const int q = lane >> 4, li = lane & 15;
  const int waveR = wave & 1, waveC = wave >> 1;
  const int bm = blockIdx.x*64, bn = blockIdx.y*64;
  const size_t aAddr = ((size_t)(bm + (t>>2)))*256 + (t&3)*8;
  const size_t bAddr = ((size_t)(bn + (t>>2)))*256 + (t&3)*8;
  const int ldsOff = (t>>2)*40 + (t&3)*8;
  f32x4 acc[2][2] = {};
  for (int k0 = 0; k0 < 256; k0 += 32){
    const f16x8 a = *(const f16x8*)&emb16[aAddr + k0];
    const f16x8 b = *(const f16x8*)&Wx16[bAddr + k0];
    __syncthreads();
    *(f16x8*)&As[ldsOff] = a;
    *(f16x8*)&Bs[ldsOff] = b;
    __syncthreads();
    #pragma unroll
    for (int rt=0; rt<2; ++rt){
      const f16x8 av = *(const f16x8*)&As[(waveR*32 + rt*16 + li)*40 + q*8];
      #pragma unroll
      for (int ct=0; ct<2; ++ct){
        const f16x8 bv = *(const f16x8*)&Bs[(waveC*32 + ct*16 + li)*40 + q*8];
        acc[rt][ct] = __builtin_amdgcn_mfma_f32_16x16x32_f16(av, bv, acc[rt][ct], 0,0,0);
      }
    }
  }
  #pragma unroll
  for (int rt=0; rt<2; ++rt)
    #pragma unroll
    for (int ct=0; ct<2; ++ct){
      const int col = bn + waveC*32 + ct*16 + li;
      #pragma unroll
      for (int reg=0; reg<4; ++reg){
        const int row = bm + waveR*32 + rt*16 + q*4 + reg;
        WxV[(size_t)row*768 + col] = (h16)acc[rt][ct][reg];
      }
    }
}

// ------------- leaves: gather WxV, cell, write h (+opt c), fold rep --------
__global__ __launch_bounds__(256) void leaf_kernel(const int* __restrict__ t1,
    const int* __restrict__ t2, const h16* __restrict__ WxV,
    const float* __restrict__ biou, h16* __restrict__ leafH,
    h16* __restrict__ leafC, int haveLeafC, float* __restrict__ rep){
  const int r = blockIdx.y, jg = blockIdx.x, k = threadIdx.x;
  const int* tp = (r < 128) ? t1 : t2;
  const int b = r & 127;
  const float bi = biou[k], bo = biou[256+k], bu = biou[512+k];
  float s = 0.f;
  for (int jj=0; jj<64; ++jj){
    const int leafIdx = jg*64 + jj;
    const size_t v = (size_t)tp[b*NTREE + 511 + leafIdx];
    const float vi = (float)WxV[v*768 + k] + bi;
    const float vo = (float)WxV[v*768 + 256 + k] + bo;
    const float vu = (float)WxV[v*768 + 512 + k] + bu;
    const float c = sigf(vi) * tanh_fast(vu);
    const float h = sigf(vo) * tanh_fast(c);
    const size_t o = ((size_t)r*512 + leafIdx)*HS + k;
    leafH[o] = (h16)h;
    if (haveLeafC) leafC[o] = (h16)c;
    s += h;
  }
  atomicAdd(&rep[r*HS + k], s);
}

// ------------- DMA-staged fused MFMA level kernel -------------
__global__ __launch_bounds__(256,3) void level_mfma(
    const h16* __restrict__ hChild, const h16* __restrict__ cChild,
    const h16* __restrict__ Wfrag,   // [cb=4][kc=8][f=16][lane=64][8]
    const h16* __restrict__ WxV,
    const int* __restrict__ t1, const int* __restrict__ t2,
    const float* __restrict__ biou, const float* __restrict__ Ufb,
    h16* __restrict__ hUp, h16* __restrict__ cPar,
    int log2n, int leafLvl, int cbN, int useCc){
  const int n = 1 << log2n;
  const int mask2 = 2*n - 1;
  const int strideR = leafLvl ? 512 : 511;
  const int childBase = leafLvl ? 0 : mask2;
  const int gatherLeaf = leafLvl && !useCc;
  __shared__ h16 ldsA[4*8*64*8];   // 32 KB
  __shared__ h16 ldsB[16*64*8];    // 16 KB
  const int t = threadIdx.x, w = t >> 6, l = t & 63;
  const int q = l >> 4, li = l & 15;
  const int waveR = w & 1, waveC = w >> 1;
  const int bx = blockIdx.x;

  // ---- stage A once: wave w stages rowFrag R=w, kc=0..7 (frag-order) ----
  {
    const int grow = bx*64 + w*16 + li;
    const int rr = grow >> (log2n + 1);
    const size_t abase = ((size_t)rr*strideR + childBase + (grow & mask2))*256;
    #pragma unroll
    for (int kc=0; kc<8; ++kc)
      DMA16(hChild + abase + kc*32 + q*8, &ldsA[(w*8 + kc)*512]);
  }

  for (int cb=0; cb<cbN; ++cb){
    const int cbi = blockIdx.y*cbN + cb;            // 64-col group 0..3
    const int colBase = cbi*64;
    const h16* wfBase = Wfrag + (size_t)cbi*8*16*512 + l*8;

    // prologue: DMA B(kc=0)
    #pragma unroll
    for (int i=0; i<4; ++i)
      DMA16(wfBase + ((size_t)(w*4 + i))*512, &ldsB[(w*4 + i)*512]);
    __syncthreads();   // drains A-DMA (cb==0) + B(0) + prior epilogue reads

    f32x4 acc[4][2][2] = {};   // [gate f,i,o,u][rt][ct]
    #pragma unroll
    for (int kc=0; kc<8; ++kc){
      f16x8 aF[2], bF[4][2];
      #pragma unroll
      for (int rt=0; rt<2; ++rt)
        aF[rt] = *(const f16x8*)&ldsA[(((waveR*2 + rt)*8 + kc)*64 + l)*8];
      #pragma unroll
      for (int g=0; g<4; ++g)
        #pragma unroll
        for (int ct=0; ct<2; ++ct)
          bF[g][ct] = *(const f16x8*)&ldsB[((g*4 + waveC*2 + ct)*64 + l)*8];
      __syncthreads();   // all reads done; nothing fresh to drain (cheap)
      if (kc < 7){
        #pragma unroll
        for (int i=0; i<4; ++i)
          DMA16(wfBase + ((size_t)(kc+1)*16 + w*4 + i)*512,
                &ldsB[(w*4 + i)*512]);
      }
      #pragma unroll
      for (int g=0; g<4; ++g)
        #pragma unroll
        for (int rt=0; rt<2; ++rt)
          #pragma unroll
          for (int ct=0; ct<2; ++ct)
            acc[g][rt][ct] = __builtin_amdgcn_mfma_f32_16x16x32_f16(
                aF[rt], bF[g][ct], acc[g][rt][ct], 0,0,0);
      __syncthreads();   // drains B(kc+1) DMA — issued before the MFMA block
    }

    // ---- epilogue (all lane-local; sibling pairs = adjacent C regs) ----
    #pragma unroll
    for (int ct=0; ct<2; ++ct){
      const int c = colBase + waveC*32 + ct*16 + li;
      const float fb  = Ufb[c];
      const float bi_ = biou[c], bo_ = biou[256+c], bu_ = biou[512+c];
      #pragma unroll
      for (int rt=0; rt<2; ++rt){
        #pragma unroll
        for (int pp=0; pp<2; ++pp){
          const int crel = waveR*32 + rt*16 + q*4 + 2*pp;  // even child row (rel)
          const int m = bx*32 + (crel >> 1);               // global parent index
          const int rr2 = m >> log2n;
          const int jn = m & (n - 1);
          const float fl = sigf(acc[0][rt][ct][2*pp]   + fb);
          const float fr = sigf(acc[0][rt][ct][2*pp+1] + fb);
          const float iv = acc[1][rt][ct][2*pp] + acc[1][rt][ct][2*pp+1] + bi_;
          const float ov = acc[2][rt][ct][2*pp] + acc[2][rt][ct][2*pp+1] + bo_;
          const float uv = acc[3][rt][ct][2*pp] + acc[3][rt][ct][2*pp+1] + bu_;
          float cl, cr;
          if (gatherLeaf){
            const int* tp = (rr2 < 128) ? t1 : t2;
            const int b = rr2 & 127;
            const size_t vl = (size_t)tp[b*NTREE + 511 + 2*jn];
            const size_t vr = (size_t)tp[b*NTREE + 512 + 2*jn];
            cl = sigf((float)WxV[vl*768 + c] + bi_) * tanh_fast((float)WxV[vl*768 + 512 + c] + bu_);
            cr = sigf((float)WxV[vr*768 + c] + bi_) * tanh_fast((float)WxV[vr*768 + 512 + c] + bu_);
          } else {
            const int cgl = bx*64 + crel;
            cl = (float)cChild[(size_t)cgl*256 + c];
            cr = (float)cChild[(size_t)(cgl+1)*256 + c];
          }
          const float cnew = sigf(iv)*tanh_fast(uv) + fl*cl + fr*cr;
          const float hnew = sigf(ov)*tanh_fast(cnew);
          hUp [((size_t)rr2*511 + (n-1) + jn)*256 + c] = (h16)hnew;
          cPar[((size_t)m)*256 + c] = (h16)cnew;
        }
      }
    }
  }
}

// ------------- rep accumulation (internal nodes, hUp) -------------
__global__ __launch_bounds__(256) void rep_accum(const h16* __restrict__ H,
    float* __restrict__ rep, int nrows, int chunk){
  const int r = blockIdx.y, k = threadIdx.x;
  const int n0 = blockIdx.x * chunk;
  int n1 = n0 + chunk; if (n1 > nrows) n1 = nrows;
  float s = 0.f;
  for (int nd = n0; nd < n1; ++nd)
    s += (float)H[((size_t)r*nrows + nd)*HS + k];
  atomicAdd(&rep[r*HS + k], s);
}

// ------------- classifier -------------
__global__ __launch_bounds__(256) void cls_kernel(const float* __restrict__ rep,
    const float* __restrict__ clsw, const float* __restrict__ clsb,
    float* __restrict__ out){
  const int b = blockIdx.x, k = threadIdx.x;
  const float d = fabsf(rep[b*HS + k] - rep[(128+b)*HS + k]) * (1.0f/1023.0f);
  __shared__ float r0[256], r1[256];
  r0[k] = d * clsw[k];
  r1[k] = d * clsw[HS + k];
  __syncthreads();
  for (int off = 128; off > 0; off >>= 1){
    if (k < off){ r0[k] += r0[k+off]; r1[k] += r1[k+off]; }
    __syncthreads();
  }
  if (k == 0){
    out[b*2 + 0] = r0[0] + clsb[0];
    out[b*2 + 1] = r1[0] + clsb[1];
  }
}

extern "C" void kernel_launch(void* const* d_in, const int* in_sizes, int n_in,
                              void* d_out, int out_size, void* d_ws, size_t ws_size,
                              hipStream_t stream){
  const int*   types1 = (const int*)d_in[0];
  const int*   types2 = (const int*)d_in[1];
  const float* emb    = (const float*)d_in[2];
  const float* Wiou   = (const float*)d_in[3];
  const float* Uiou   = (const float*)d_in[4];
  const float* biou   = (const float*)d_in[5];
  const float* Ufw    = (const float*)d_in[6];
  const float* Ufb    = (const float*)d_in[7];
  const float* clsw   = (const float*)d_in[8];
  const float* clsb   = (const float*)d_in[9];
  float* out = (float*)d_out;

  h16* WxV   = (h16*)d_ws;                        // 24,576,000
  h16* leafH = WxV   + 24576000UL;                // 33,554,432
  h16* hUp   = leafH + 33554432UL;                // 33,488,896
  h16* cA    = hUp   + 33488896UL;                // 16,777,216
  h16* cB    = cA    + 16777216UL;                //  8,388,608
  h16* emb16 = cB;                                //  8,192,000 (overlay on cB)
  h16* Wx16  = cB + 8192000UL;                    //    196,608 (overlay on cB)
  float* rep = (float*)(cB + 8388608UL);          //     65,536 fp32
  h16* W16   = (h16*)(rep + 65536UL);             //    262,144
  h16* Wfrag = W16 + 262144UL;                    //    524,288 (1 MB)
  h16* leafC = Wfrag + 524288UL;                  // 33,554,432 (optional, 67 MB)
  const int haveLeafC = (ws_size >= 302600000UL) ? 1 : 0;

  convert_all<<<4224, 256, 0, stream>>>(emb, Ufw, Uiou, Wiou, emb16, W16, Wx16, rep);
  swizzle_w<<<256, 256, 0, stream>>>(W16, Wfrag);
  wxv_mfma<<<dim3(500,12), 256, 0, stream>>>(emb16, Wx16, WxV);
  leaf_kernel<<<dim3(8, B2), 256, 0, stream>>>(types1, types2, WxV, biou,
                                               leafH, leafC, haveLeafC, rep);

  const h16* cprev = nullptr;
  for (int lvl = 8; lvl >= 0; --lvl){
    const int children = 512 << lvl;        // B2 * 2n
    const int cbN = (lvl >= 6) ? 4 : 1;     // big levels: y=1, col loop in-block
    h16* cout = ((8 - lvl) & 1) ? cB : cA;
    const h16* cin = (lvl == 8) ? (haveLeafC ? leafC : nullptr) : cprev;
    level_mfma<<<dim3(children/64, 4/cbN), 256, 0, stream>>>(
        (lvl == 8) ? leafH : hUp, cin, Wfrag, WxV, types1, types2,
        biou, Ufb, hUp, cout, lvl, (lvl == 8) ? 1 : 0, cbN,
        (lvl == 8) ? haveLeafC : 1);
    cprev = cout;
  }
  rep_accum<<<dim3(4, B2), 256, 0, stream>>>(hUp, rep, 511, 128);
  cls_kernel<<<128, 256, 0, stream>>>(rep, clsw, clsb, out);
}